// Round 9
// baseline (507.367 us; speedup 1.0000x reference)
//
#include <hip/hip_runtime.h>

#define N_NODES 50000
#define N_EDGES 800000
#define N_GRAPHS 256
#define F 100  // hidden dim

#define SCAN_B 512
#define SCAN_NB 98          // 98*512 = 50176 >= 50001
#define SCAN_PAD (SCAN_NB * SCAN_B)

#define PART_SZ 6250        // 8 dst partitions * 6250 = 50000
#define FILL_CHUNK 2048
#define HIST_BLOCKS 3128    // 391 chunks * 8 partitions

#define SROW 72             // conv1 LDS row stride in shorts
#define EPS 264             // conv1 epilogue LDS row stride in shorts
#define AST2 272            // fused A-tile row stride in shorts (544B: 16B-aligned)

#define SENT N_NODES        // sentinel row index (zeroed) for CSR padding
#define CSR_CAP 1155072     // 282*4096 ints >= 800000 + 50000*7 + slack

typedef __attribute__((ext_vector_type(8))) short bf16x8;
typedef __attribute__((ext_vector_type(4))) float f32x4;
typedef unsigned short ushort_t;
typedef unsigned int uint_t;

__device__ inline ushort_t f2bf(float f) {  // RNE float->bf16
  uint_t u = __float_as_uint(f);
  uint_t r = (u + 0x7fffu + ((u >> 16) & 1u)) >> 16;
  return (ushort_t)r;
}

// ---------------- D1: merged packing + cnt zeroing + csr sentinel prefill ----------------

__global__ __launch_bounds__(256) void pack_all(
    const float* __restrict__ w1_rel, const float* __restrict__ w1_root,
    const float* __restrict__ w_rel, const float* __restrict__ w_root,
    ushort_t* __restrict__ Wp1, ushort_t* __restrict__ Wf, int* __restrict__ cnt,
    int* __restrict__ csr, ushort_t* __restrict__ ZP,
    ushort_t* __restrict__ H1, ushort_t* __restrict__ H2) {
  int b = blockIdx.x;
  int tid = threadIdx.x;
  if (b < 208) {
    int row = b;
    for (int k = tid; k < 384; k += 256) {
      float v = 0.f;
      if (k < 336) {
        if (row < 100) v = w1_rel[row * 336 + k];
        else if (row < 200) v = w1_root[(row - 100) * 336 + k];
      }
      Wp1[(size_t)row * 384 + k] = f2bf(v);
    }
  } else if (b < 720) {
    int rowl = b - 208;           // l*128 + row
    int l = rowl >> 7, row = rowl & 127;
    int k = tid;                  // 0..255
    float v = 0.f;
    if (row < 100) {
      if (k < 100) v = w_rel[((size_t)l * 100 + row) * 100 + k];
      else if (k >= 128 && k < 228) v = w_root[((size_t)l * 100 + row) * 100 + (k - 128)];
    }
    Wf[(size_t)rowl * 256 + k] = f2bf(v);
  } else if (b < 769) {
    int z = b - 720;              // 0..48, each zeroes 1024 ints
    *(int4*)(cnt + (size_t)z * 1024 + tid * 4) = make_int4(0, 0, 0, 0);
  } else if (b < 1051) {
    int i0 = (b - 769) * 4096 + tid * 16;
    int4 sv = make_int4(SENT, SENT, SENT, SENT);
    *(int4*)(csr + i0) = sv; *(int4*)(csr + i0 + 4) = sv;
    *(int4*)(csr + i0 + 8) = sv; *(int4*)(csr + i0 + 12) = sv;
  } else {
    uint4 z4 = make_uint4(0u, 0u, 0u, 0u);
    if (tid < 32)      *(uint4*)(ZP + (size_t)SENT * 256 + tid * 8) = z4;
    else if (tid < 48) *(uint4*)(H1 + (size_t)SENT * 128 + (tid - 32) * 8) = z4;
    else if (tid < 64) *(uint4*)(H2 + (size_t)SENT * 128 + (tid - 48) * 8) = z4;
  }
}

// ---------------- D2: hist ----------------

__global__ __launch_bounds__(256) void hist_kernel(const int* __restrict__ dst,
                                                   int* __restrict__ cnt, int E) {
  int part = blockIdx.x & 7;
  int lo = part * PART_SZ, hi = lo + PART_SZ;
  int base = (blockIdx.x >> 3) * FILL_CHUNK;
  int end = base + FILL_CHUNK; if (end > E) end = E;
  for (int i = base + threadIdx.x; i < end; i += 256) {
    int d = dst[i];
    if (d >= lo && d < hi) atomicAdd(&cnt[d], 1);
  }
}

// ---------------- D3-5: 3-phase parallel scan, slots padded to multiples of 8 ----------------

__global__ __launch_bounds__(SCAN_B) void scan1_kernel(const int* __restrict__ cnt,
                                                       int* __restrict__ excl,
                                                       int* __restrict__ bsum) {
  __shared__ int sh[SCAN_B];
  int t = threadIdx.x;
  int i = blockIdx.x * SCAN_B + t;
  int v = (cnt[i] + 7) & ~7;     // padded slot size
  sh[t] = v;
  __syncthreads();
  for (int off = 1; off < SCAN_B; off <<= 1) {
    int u = (t >= off) ? sh[t - off] : 0;
    __syncthreads();
    sh[t] += u;
    __syncthreads();
  }
  excl[i] = sh[t] - v;
  if (t == SCAN_B - 1) bsum[blockIdx.x] = sh[t];
}

__global__ __launch_bounds__(128) void scan2_kernel(int* __restrict__ bsum) {
  __shared__ int sh[128];
  int t = threadIdx.x;
  int v = (t < SCAN_NB) ? bsum[t] : 0;
  sh[t] = v;
  __syncthreads();
  for (int off = 1; off < 128; off <<= 1) {
    int u = (t >= off) ? sh[t - off] : 0;
    __syncthreads();
    sh[t] += u;
    __syncthreads();
  }
  if (t < SCAN_NB) bsum[t] = sh[t] - v;
}

__global__ __launch_bounds__(SCAN_B) void scan3_kernel(const int* __restrict__ excl,
                                                       const int* __restrict__ bsum,
                                                       int* __restrict__ offs,
                                                       int* __restrict__ cursor) {
  int i = blockIdx.x * SCAN_B + threadIdx.x;
  int v = excl[i] + bsum[blockIdx.x];
  if (i <= N_NODES) { offs[i] = v; cursor[i] = v; }
}

// ---------------- D6: fill (real edges into [offs, offs+cnt); pads stay SENT) ----------------

__global__ __launch_bounds__(256) void fill_kernel(const int* __restrict__ src,
                                                   const int* __restrict__ dst,
                                                   int* __restrict__ cursor,
                                                   int* __restrict__ csr_src, int E) {
  int part = blockIdx.x & 7;
  int lo = part * PART_SZ, hi = lo + PART_SZ;
  int base = (blockIdx.x >> 3) * FILL_CHUNK;
  int end = base + FILL_CHUNK; if (end > E) end = E;
  for (int i = base + threadIdx.x; i < end; i += 256) {
    int d = dst[i];
    if (d >= lo && d < hi) {
      int p = atomicAdd(&cursor[d], 1);
      csr_src[p] = src[i];
    }
  }
}

// ---------------- D7: layer-1 conv (R1-verified: LDS staging + LDS-transpose epilogue) ----------

template <bool AF32>
__global__ __launch_bounds__(256) void conv_mfma(
    const void* __restrict__ Aptr, const ushort_t* __restrict__ Wp,
    const float* __restrict__ bias,
    ushort_t* __restrict__ ZP, int Kp) {
  __shared__ short smem[64 * SROW + 208 * SROW];
  __shared__ float bias_s[104];
  short* alds = smem;
  short* blds = smem + 64 * SROW;

  int tid = threadIdx.x;
  int n0 = blockIdx.x * 64;
  if (tid < 100) bias_s[tid] = bias[tid];

  f32x4 acc[13];
#pragma unroll
  for (int b = 0; b < 13; ++b) acc[b] = (f32x4)0.f;

  int w = tid >> 6, lane = tid & 63, q = lane >> 4, m16 = lane & 15;

  int ar[2], aq[2];
#pragma unroll
  for (int u = 0; u < 2; ++u) { int c = tid + u * 256; ar[u] = c >> 3; aq[u] = c & 7; }

  bf16x8 areg[2], breg[7];

  auto load_chunk = [&](int k0) {
#pragma unroll
    for (int u = 0; u < 2; ++u) {
      int node = n0 + ar[u];
      int k = k0 + aq[u] * 8;
      bf16x8 val = (bf16x8)0;
      if (AF32) {
        if (node < N_NODES && k < 336) {
          const float* p = (const float*)Aptr + (size_t)node * 336 + k;
          float4 f0 = *(const float4*)p;
          float4 f1 = *(const float4*)(p + 4);
          val[0] = (short)f2bf(f0.x); val[1] = (short)f2bf(f0.y);
          val[2] = (short)f2bf(f0.z); val[3] = (short)f2bf(f0.w);
          val[4] = (short)f2bf(f1.x); val[5] = (short)f2bf(f1.y);
          val[6] = (short)f2bf(f1.z); val[7] = (short)f2bf(f1.w);
        }
      } else {
        if (node < N_NODES)
          val = *(const bf16x8*)((const short*)Aptr + (size_t)node * 128 + k);
      }
      areg[u] = val;
    }
#pragma unroll
    for (int u = 0; u < 7; ++u) {
      int c = tid + u * 256;
      if (c < 1664) {
        int r = c >> 3, qq = c & 7;
        breg[u] = *(const bf16x8*)((const short*)Wp + (size_t)r * Kp + k0 + qq * 8);
      }
    }
  };

  load_chunk(0);

  for (int k0 = 0; k0 < Kp; k0 += 64) {
#pragma unroll
    for (int u = 0; u < 2; ++u)
      *(bf16x8*)&alds[ar[u] * SROW + aq[u] * 8] = areg[u];
#pragma unroll
    for (int u = 0; u < 7; ++u) {
      int c = tid + u * 256;
      if (c < 1664) {
        int r = c >> 3, qq = c & 7;
        *(bf16x8*)&blds[r * SROW + qq * 8] = breg[u];
      }
    }
    __syncthreads();
    if (k0 + 64 < Kp) load_chunk(k0 + 64);
#pragma unroll
    for (int s = 0; s < 2; ++s) {
      bf16x8 a = *(const bf16x8*)&alds[(w * 16 + m16) * SROW + s * 32 + q * 8];
#pragma unroll
      for (int b = 0; b < 13; ++b) {
        bf16x8 bf = *(const bf16x8*)&blds[(b * 16 + m16) * SROW + s * 32 + q * 8];
        acc[b] = __builtin_amdgcn_mfma_f32_16x16x32_bf16(a, bf, acc[b], 0, 0, 0);
      }
    }
    __syncthreads();
  }

  // epilogue: zero pad cols, transpose through LDS, full-line coalesced stores
  short* ep = smem;
#pragma unroll
  for (int j = 0; j < 9; ++j) {        // zero ep region (64*EPS shorts = 2112 uint4)
    int i = tid + j * 256;
    if (i < 64 * EPS / 8) *(uint4*)&ep[i * 8] = make_uint4(0u, 0u, 0u, 0u);
  }
  __syncthreads();
#pragma unroll
  for (int b = 0; b < 13; ++b) {
    int n = b * 16 + m16;
    if (n < 200) {
      int c = (n < 100) ? n : (n + 28);
      float add = (n < 100) ? 0.f : bias_s[(n - 100) & 127];
#pragma unroll
      for (int r = 0; r < 4; ++r) {
        int row = w * 16 + q * 4 + r;
        ep[row * EPS + c] = (short)f2bf(acc[b][r] + add);
      }
    }
  }
  __syncthreads();
#pragma unroll
  for (int j = 0; j < 8; ++j) {
    int i = tid + j * 256;
    int row = i >> 5, c16 = i & 31;
    int node = n0 + row;
    if (node < N_NODES) {
      *(uint4*)(ZP + (size_t)node * 256 + c16 * 8) =
          *(const uint4*)&ep[row * EPS + c16 * 8];
    }
  }
}

// ---------------- D8: gather1 — R8 edge-STREAMING (dst-sorted CSR, 16 dsts/wave) -------------

__global__ __launch_bounds__(256) void gather_stream(
    const ushort_t* __restrict__ ZP,
    const int* __restrict__ offs, const int* __restrict__ csr,
    ushort_t* __restrict__ H) {
  int lane = threadIdx.x & 63;
  int wid = threadIdx.x >> 6;
  int d0 = __builtin_amdgcn_readfirstlane(blockIdx.x * 64 + wid * 16);
  if (d0 >= N_NODES) return;
  int dlim = d0 + 16; if (dlim > N_NODES) dlim = N_NODES;
  int offc = (lane < 50 ? lane : 49) * 2;   // clamped ushort offset (payload cols)

  float p0 = 0.f, p1 = 0.f;
  int d = d0;

  auto flushd = [&](int dd, float a0, float a1) {
    uint_t zr = *(const uint_t*)(ZP + (size_t)dd * 256 + 128 + offc);  // Zroot
    a0 += __uint_as_float(zr << 16);
    a1 += __uint_as_float(zr & 0xffff0000u);
    a0 = fmaxf(a0, 0.f); a1 = fmaxf(a1, 0.f);
    uint_t o = (uint_t)f2bf(a0) | ((uint_t)f2bf(a1) << 16);
    if (lane >= 50) o = 0u;
    *(uint_t*)(H + (size_t)dd * 128 + lane * 2) = o;
  };

  int s0 = offs[d0], e0 = offs[dlim];
  int nextoff = offs[d + 1];
  uint_t bA[8], bB[8];
  auto issue = [&](uint_t (&buf)[8], int i) {
    int4 sa = *(const int4*)(csr + i);
    int4 sb = *(const int4*)(csr + i + 4);
    buf[0] = *(const uint_t*)(ZP + (size_t)sa.x * 256 + offc);
    buf[1] = *(const uint_t*)(ZP + (size_t)sa.y * 256 + offc);
    buf[2] = *(const uint_t*)(ZP + (size_t)sa.z * 256 + offc);
    buf[3] = *(const uint_t*)(ZP + (size_t)sa.w * 256 + offc);
    buf[4] = *(const uint_t*)(ZP + (size_t)sb.x * 256 + offc);
    buf[5] = *(const uint_t*)(ZP + (size_t)sb.y * 256 + offc);
    buf[6] = *(const uint_t*)(ZP + (size_t)sb.z * 256 + offc);
    buf[7] = *(const uint_t*)(ZP + (size_t)sb.w * 256 + offc);
  };
  auto cons = [&](uint_t (&buf)[8]) {
#pragma unroll
    for (int t = 0; t < 8; ++t) {
      p0 += __uint_as_float(buf[t] << 16);
      p1 += __uint_as_float(buf[t] & 0xffff0000u);
    }
  };

  int i = s0;
  if (i < e0) issue(bA, i);
  while (i < e0) {
    if (i + 8 < e0) issue(bB, i + 8);
    while (i == nextoff) { flushd(d, p0, p1); p0 = 0.f; p1 = 0.f; ++d; nextoff = offs[d + 1]; }
    cons(bA);
    i += 8;
    if (i >= e0) break;
    if (i + 8 < e0) issue(bA, i + 8);
    while (i == nextoff) { flushd(d, p0, p1); p0 = 0.f; p1 = 0.f; ++d; nextoff = offs[d + 1]; }
    cons(bB);
    i += 8;
  }
  while (d < dlim) { flushd(d, p0, p1); p0 = 0.f; p1 = 0.f; ++d; }
}

// ---------------- D9-12: fused layer — R8 streaming gather + 64-node MFMA tile --------------
// R9 FIX: own-h copy writes A-tile cols 128..255 (short offset 128 + lane*2), NOT 256+...
// (R8 bug: 256+lane*2 overflowed the 272-short row into the next row AND left K-cols
// 128..255 uninitialized -> MFMA consumed garbage -> absmax inf.)

__global__ __launch_bounds__(256) void fused_stream(
    const ushort_t* __restrict__ Hin,
    const ushort_t* __restrict__ Wf,    // [128][256] bf16
    const float* __restrict__ bias,     // [100]
    const int* __restrict__ offs, const int* __restrict__ csr,
    ushort_t* __restrict__ Hout) {
  __shared__ short alds[64 * AST2];
  __shared__ __align__(16) float bias_s[128];

  int tid = threadIdx.x;
  int lane = tid & 63, wid = tid >> 6;
  int q = lane >> 4, m16 = lane & 15;
  if (tid < 128) bias_s[tid] = (tid < 100) ? bias[tid] : 0.f;

  int bd0 = blockIdx.x * 64;
  int d0 = __builtin_amdgcn_readfirstlane(bd0 + wid * 16);

  float p0 = 0.f, p1 = 0.f;
  auto flushA = [&](int dd, float a0, float a1) {
    uint_t o = (uint_t)f2bf(a0) | ((uint_t)f2bf(a1) << 16);
    *(uint_t*)&alds[(dd - bd0) * AST2 + lane * 2] = o;
  };

  if (d0 < N_NODES) {
    int dlim = d0 + 16; if (dlim > N_NODES) dlim = N_NODES;
    int s0 = offs[d0], e0 = offs[dlim];
    int d = d0;
    int nextoff = offs[d + 1];
    uint_t bA[8], bB[8];
    auto issue = [&](uint_t (&buf)[8], int i) {
      int4 sa = *(const int4*)(csr + i);
      int4 sb = *(const int4*)(csr + i + 4);
      buf[0] = *(const uint_t*)(Hin + (size_t)sa.x * 128 + lane * 2);
      buf[1] = *(const uint_t*)(Hin + (size_t)sa.y * 128 + lane * 2);
      buf[2] = *(const uint_t*)(Hin + (size_t)sa.z * 128 + lane * 2);
      buf[3] = *(const uint_t*)(Hin + (size_t)sa.w * 128 + lane * 2);
      buf[4] = *(const uint_t*)(Hin + (size_t)sb.x * 128 + lane * 2);
      buf[5] = *(const uint_t*)(Hin + (size_t)sb.y * 128 + lane * 2);
      buf[6] = *(const uint_t*)(Hin + (size_t)sb.z * 128 + lane * 2);
      buf[7] = *(const uint_t*)(Hin + (size_t)sb.w * 128 + lane * 2);
    };
    auto cons = [&](uint_t (&buf)[8]) {
#pragma unroll
      for (int t = 0; t < 8; ++t) {
        p0 += __uint_as_float(buf[t] << 16);
        p1 += __uint_as_float(buf[t] & 0xffff0000u);
      }
    };
    int i = s0;
    if (i < e0) issue(bA, i);
    while (i < e0) {
      if (i + 8 < e0) issue(bB, i + 8);
      while (i == nextoff) { flushA(d, p0, p1); p0 = 0.f; p1 = 0.f; ++d; nextoff = offs[d + 1]; }
      cons(bA);
      i += 8;
      if (i >= e0) break;
      if (i + 8 < e0) issue(bA, i + 8);
      while (i == nextoff) { flushA(d, p0, p1); p0 = 0.f; p1 = 0.f; ++d; nextoff = offs[d + 1]; }
      cons(bB);
      i += 8;
    }
    while (d < d0 + 16) { flushA(d, p0, p1); p0 = 0.f; p1 = 0.f; ++d; }
  } else {
    for (int dd = d0; dd < d0 + 16; ++dd) flushA(dd, 0.f, 0.f);
  }

  // own-h copy: A-tile cols 128..255 (H pad cols 100..127 are zero) — R9 FIX: +128
  for (int r = 0; r < 16; ++r) {
    int dd = d0 + r;
    int srcrow = (dd < N_NODES) ? dd : SENT;
    uint_t hv = *(const uint_t*)(Hin + (size_t)srcrow * 128 + lane * 2);
    *(uint_t*)&alds[(dd - bd0) * AST2 + 128 + lane * 2] = hv;
  }
  __syncthreads();

  // MFMA: out[node = wid*16+m16][wrow = wb*16+q*4+r], K=256
  f32x4 acc[8];
#pragma unroll
  for (int wb = 0; wb < 8; ++wb) acc[wb] = (f32x4)0.f;
#pragma unroll
  for (int kb = 0; kb < 8; ++kb) {
    bf16x8 af = *(const bf16x8*)&alds[(wid * 16 + m16) * AST2 + kb * 32 + q * 8];
#pragma unroll
    for (int wb = 0; wb < 8; ++wb) {
      bf16x8 wf = *(const bf16x8*)(Wf + (size_t)(wb * 16 + m16) * 256 + kb * 32 + q * 8);
      acc[wb] = __builtin_amdgcn_mfma_f32_16x16x32_bf16(wf, af, acc[wb], 0, 0, 0);
    }
  }
  __syncthreads();   // all A-tile reads done; reuse alds as epilogue buffer

  // transpose epilogue: ep[node row][wrow col], bias+relu+bf16
#pragma unroll
  for (int wb = 0; wb < 8; ++wb) {
    int col0 = wb * 16 + q * 4;
    float4 bb = *(const float4*)&bias_s[col0];   // zeros for col0 >= 100
    ushort4 v;
    v.x = f2bf(fmaxf(acc[wb][0] + bb.x, 0.f));
    v.y = f2bf(fmaxf(acc[wb][1] + bb.y, 0.f));
    v.z = f2bf(fmaxf(acc[wb][2] + bb.z, 0.f));
    v.w = f2bf(fmaxf(acc[wb][3] + bb.w, 0.f));
    *(ushort4*)&alds[(wid * 16 + m16) * AST2 + col0] = v;
  }
  __syncthreads();

  // coalesced stores: 64 rows x 128 shorts = 1024 uint4
#pragma unroll
  for (int j = 0; j < 4; ++j) {
    int i2 = tid + j * 256;
    int row = i2 >> 4, c = i2 & 15;
    int node = bd0 + row;
    if (node < N_NODES)
      *(uint4*)(Hout + (size_t)node * 128 + c * 8) = *(const uint4*)&alds[row * AST2 + c * 8];
  }
}

// ---------------- D13: fused pool + MLP head ----------------

__global__ __launch_bounds__(1024) void pool_mlp(
    const ushort_t* __restrict__ H, const int* __restrict__ batch,
    const float* __restrict__ lw1, const float* __restrict__ lb1,
    const float* __restrict__ lw2, const float* __restrict__ lb2,
    const float* __restrict__ lw3, const float* __restrict__ lb3,
    float* __restrict__ out) {
  int g = blockIdx.x;
  int t = threadIdx.x;
  int lo = 0, hi = N_NODES;
  while (lo < hi) { int mid = (lo + hi) >> 1; if (batch[mid] < g) lo = mid + 1; else hi = mid; }
  int s = lo;
  hi = N_NODES;
  while (lo < hi) { int mid = (lo + hi) >> 1; if (batch[mid] <= g) lo = mid + 1; else hi = mid; }
  int e = lo;

  int row = t >> 6;      // 16 node-rows
  int lane = t & 63;
  int off = (lane < 50 ? lane : 49) * 2;
  float a0 = 0.f, a1 = 0.f;
  for (int n = s + row; n < e; n += 16) {
    uint_t z = *(const uint_t*)(H + (size_t)n * 128 + off);
    a0 += __uint_as_float(z << 16);
    a1 += __uint_as_float(z & 0xffff0000u);
  }
  __shared__ float sh[16][104];
  __shared__ float r0[F], r1[F], r2[F];
  if (lane < 50) { sh[row][lane * 2] = a0; sh[row][lane * 2 + 1] = a1; }
  __syncthreads();
  if (t < F) {
    float acc = 0.f;
#pragma unroll
    for (int r = 0; r < 16; ++r) acc += sh[r][t];
    int cnt = e - s;
    float d = (cnt > 0) ? (float)cnt : 1.f;
    r0[t] = acc / d;
  }
  __syncthreads();
  if (t < F) {
    float sv = lb1[t];
    for (int k = 0; k < F; ++k) sv += r0[k] * lw1[t * F + k];
    r1[t] = fmaxf(sv, 0.f);
  }
  __syncthreads();
  if (t < F) {
    float sv = lb2[t];
    for (int k = 0; k < F; ++k) sv += r1[k] * lw2[t * F + k];
    r2[t] = fmaxf(sv, 0.f);
  }
  __syncthreads();
  if (t < 29) {
    float sv = lb3[t];
    for (int k = 0; k < F; ++k) sv += r2[k] * lw3[t * F + k];
    out[g * 29 + t] = sv;
  }
}

// ---------------- launch ------------------------------------------------------------------------

extern "C" void kernel_launch(void* const* d_in, const int* in_sizes, int n_in,
                              void* d_out, int out_size, void* d_ws, size_t ws_size,
                              hipStream_t stream) {
  const float* x       = (const float*)d_in[0];
  const int*   ei      = (const int*)d_in[1];
  const int*   batch   = (const int*)d_in[2];
  const float* w1_rel  = (const float*)d_in[3];
  const float* w1_root = (const float*)d_in[4];
  const float* b1      = (const float*)d_in[5];
  const float* w_rel   = (const float*)d_in[6];
  const float* w_root  = (const float*)d_in[7];
  const float* bvec    = (const float*)d_in[8];
  const float* lw1     = (const float*)d_in[9];
  const float* lb1     = (const float*)d_in[10];
  const float* lw2     = (const float*)d_in[11];
  const float* lb2     = (const float*)d_in[12];
  const float* lw3     = (const float*)d_in[13];
  const float* lb3     = (const float*)d_in[14];
  float* out = (float*)d_out;

  // workspace layout (sentinel row at index N_NODES in H1/H2/ZP)
  char* ws = (char*)d_ws;
  size_t o = 0;
  auto alloc = [&](size_t bytes) { void* p = ws + o; o = (o + bytes + 511) & ~(size_t)511; return p; };
  ushort_t* H1   = (ushort_t*)alloc((size_t)(N_NODES + 64) * 128 * 2);
  ushort_t* H2   = (ushort_t*)alloc((size_t)(N_NODES + 64) * 128 * 2);
  ushort_t* ZP   = (ushort_t*)alloc((size_t)(N_NODES + 1) * 256 * 2);
  ushort_t* Wp1  = (ushort_t*)alloc((size_t)208 * 384 * 2);
  ushort_t* Wf   = (ushort_t*)alloc((size_t)4 * 128 * 256 * 2);
  int* cnt    = (int*)alloc((size_t)SCAN_PAD * 4);
  int* excl   = (int*)alloc((size_t)SCAN_PAD * 4);
  int* bsum   = (int*)alloc((size_t)128 * 4);
  int* offs   = (int*)alloc((size_t)(N_NODES + 1) * 4);
  int* cursor = (int*)alloc((size_t)(N_NODES + 1) * 4);
  int* csr    = (int*)alloc((size_t)CSR_CAP * 4);

  const int E = N_EDGES;
  const int* srcv = ei;
  const int* dstv = ei + E;

  pack_all<<<1052, 256, 0, stream>>>(w1_rel, w1_root, w_rel, w_root, Wp1, Wf, cnt, csr, ZP, H1, H2);
  hist_kernel<<<HIST_BLOCKS, 256, 0, stream>>>(dstv, cnt, E);
  scan1_kernel<<<SCAN_NB, SCAN_B, 0, stream>>>(cnt, excl, bsum);
  scan2_kernel<<<1, 128, 0, stream>>>(bsum);
  scan3_kernel<<<SCAN_NB, SCAN_B, 0, stream>>>(excl, bsum, offs, cursor);
  fill_kernel<<<HIST_BLOCKS, 256, 0, stream>>>(srcv, dstv, cursor, csr, E);

  int mmgrid = (N_NODES + 63) / 64;  // 782
  conv_mfma<true><<<mmgrid, 256, 0, stream>>>(x, Wp1, b1, ZP, 384);
  gather_stream<<<(N_NODES + 63) / 64, 256, 0, stream>>>(ZP, offs, csr, H1);

  const ushort_t* hin = H1;
  ushort_t* hout = H2;
  for (int l = 0; l < 4; ++l) {
    fused_stream<<<(N_NODES + 63) / 64, 256, 0, stream>>>(hin, Wf + (size_t)l * 128 * 256,
                                                          bvec + (size_t)l * F, offs, csr, hout);
    const ushort_t* tmp = hout; hout = (ushort_t*)hin; hin = tmp;
  }
  // after 4 swaps hin == H1
  pool_mlp<<<N_GRAPHS, 1024, 0, stream>>>(hin, batch, lw1, lb1, lw2, lb2, lw3, lb3, out);
}

// Round 10
// 495.174 us; speedup vs baseline: 1.0246x; 1.0246x over previous
//
#include <hip/hip_runtime.h>

#define N_NODES 50000
#define N_EDGES 800000
#define N_GRAPHS 256
#define F 100  // hidden dim

#define SCAN_B 512
#define SCAN_NB 98          // 98*512 = 50176 >= 50001
#define SCAN_PAD (SCAN_NB * SCAN_B)

#define PART_SZ 6250        // 8 dst partitions * 6250 = 50000
#define FILL_CHUNK 2048
#define HIST_BLOCKS 3128    // 391 chunks * 8 partitions

#define SROW 72             // conv1 LDS row stride in shorts
#define EPS 264             // conv1 epilogue LDS row stride in shorts
#define AST2 272            // fused A-tile row stride in shorts (544B: 16B-aligned)

#define SENT N_NODES        // sentinel row index (zeroed) for CSR padding
#define CSR_CAP 1155072     // 282*4096 ints >= 800000 + 50000*7 + slack

typedef __attribute__((ext_vector_type(8))) short bf16x8;
typedef __attribute__((ext_vector_type(4))) float f32x4;
typedef unsigned short ushort_t;
typedef unsigned int uint_t;

__device__ inline ushort_t f2bf(float f) {  // RNE float->bf16
  uint_t u = __float_as_uint(f);
  uint_t r = (u + 0x7fffu + ((u >> 16) & 1u)) >> 16;
  return (ushort_t)r;
}

// ---------------- D1: merged packing + cnt zeroing + csr sentinel prefill ----------------

__global__ __launch_bounds__(256) void pack_all(
    const float* __restrict__ w1_rel, const float* __restrict__ w1_root,
    const float* __restrict__ w_rel, const float* __restrict__ w_root,
    ushort_t* __restrict__ Wp1, ushort_t* __restrict__ Wf, int* __restrict__ cnt,
    int* __restrict__ csr, ushort_t* __restrict__ ZP,
    ushort_t* __restrict__ H1, ushort_t* __restrict__ H2) {
  int b = blockIdx.x;
  int tid = threadIdx.x;
  if (b < 208) {
    int row = b;
    for (int k = tid; k < 384; k += 256) {
      float v = 0.f;
      if (k < 336) {
        if (row < 100) v = w1_rel[row * 336 + k];
        else if (row < 200) v = w1_root[(row - 100) * 336 + k];
      }
      Wp1[(size_t)row * 384 + k] = f2bf(v);
    }
  } else if (b < 720) {
    int rowl = b - 208;           // l*128 + row
    int l = rowl >> 7, row = rowl & 127;
    int k = tid;                  // 0..255
    float v = 0.f;
    if (row < 100) {
      if (k < 100) v = w_rel[((size_t)l * 100 + row) * 100 + k];
      else if (k >= 128 && k < 228) v = w_root[((size_t)l * 100 + row) * 100 + (k - 128)];
    }
    Wf[(size_t)rowl * 256 + k] = f2bf(v);
  } else if (b < 769) {
    int z = b - 720;              // 0..48, each zeroes 1024 ints
    *(int4*)(cnt + (size_t)z * 1024 + tid * 4) = make_int4(0, 0, 0, 0);
  } else if (b < 1051) {
    int i0 = (b - 769) * 4096 + tid * 16;
    int4 sv = make_int4(SENT, SENT, SENT, SENT);
    *(int4*)(csr + i0) = sv; *(int4*)(csr + i0 + 4) = sv;
    *(int4*)(csr + i0 + 8) = sv; *(int4*)(csr + i0 + 12) = sv;
  } else {
    uint4 z4 = make_uint4(0u, 0u, 0u, 0u);
    if (tid < 32)      *(uint4*)(ZP + (size_t)SENT * 256 + tid * 8) = z4;
    else if (tid < 48) *(uint4*)(H1 + (size_t)SENT * 128 + (tid - 32) * 8) = z4;
    else if (tid < 64) *(uint4*)(H2 + (size_t)SENT * 128 + (tid - 48) * 8) = z4;
  }
}

// ---------------- D2: hist ----------------

__global__ __launch_bounds__(256) void hist_kernel(const int* __restrict__ dst,
                                                   int* __restrict__ cnt, int E) {
  int part = blockIdx.x & 7;
  int lo = part * PART_SZ, hi = lo + PART_SZ;
  int base = (blockIdx.x >> 3) * FILL_CHUNK;
  int end = base + FILL_CHUNK; if (end > E) end = E;
  for (int i = base + threadIdx.x; i < end; i += 256) {
    int d = dst[i];
    if (d >= lo && d < hi) atomicAdd(&cnt[d], 1);
  }
}

// ---------------- D3-5: 3-phase parallel scan, slots padded to multiples of 8 ----------------

__global__ __launch_bounds__(SCAN_B) void scan1_kernel(const int* __restrict__ cnt,
                                                       int* __restrict__ excl,
                                                       int* __restrict__ bsum) {
  __shared__ int sh[SCAN_B];
  int t = threadIdx.x;
  int i = blockIdx.x * SCAN_B + t;
  int v = (cnt[i] + 7) & ~7;     // padded slot size
  sh[t] = v;
  __syncthreads();
  for (int off = 1; off < SCAN_B; off <<= 1) {
    int u = (t >= off) ? sh[t - off] : 0;
    __syncthreads();
    sh[t] += u;
    __syncthreads();
  }
  excl[i] = sh[t] - v;
  if (t == SCAN_B - 1) bsum[blockIdx.x] = sh[t];
}

__global__ __launch_bounds__(128) void scan2_kernel(int* __restrict__ bsum) {
  __shared__ int sh[128];
  int t = threadIdx.x;
  int v = (t < SCAN_NB) ? bsum[t] : 0;
  sh[t] = v;
  __syncthreads();
  for (int off = 1; off < 128; off <<= 1) {
    int u = (t >= off) ? sh[t - off] : 0;
    __syncthreads();
    sh[t] += u;
    __syncthreads();
  }
  if (t < SCAN_NB) bsum[t] = sh[t] - v;
}

__global__ __launch_bounds__(SCAN_B) void scan3_kernel(const int* __restrict__ excl,
                                                       const int* __restrict__ bsum,
                                                       int* __restrict__ offs,
                                                       int* __restrict__ cursor) {
  int i = blockIdx.x * SCAN_B + threadIdx.x;
  int v = excl[i] + bsum[blockIdx.x];
  if (i <= N_NODES) { offs[i] = v; cursor[i] = v; }
}

// ---------------- D6: fill (real edges into [offs, offs+cnt); pads stay SENT) ----------------

__global__ __launch_bounds__(256) void fill_kernel(const int* __restrict__ src,
                                                   const int* __restrict__ dst,
                                                   int* __restrict__ cursor,
                                                   int* __restrict__ csr_src, int E) {
  int part = blockIdx.x & 7;
  int lo = part * PART_SZ, hi = lo + PART_SZ;
  int base = (blockIdx.x >> 3) * FILL_CHUNK;
  int end = base + FILL_CHUNK; if (end > E) end = E;
  for (int i = base + threadIdx.x; i < end; i += 256) {
    int d = dst[i];
    if (d >= lo && d < hi) {
      int p = atomicAdd(&cursor[d], 1);
      csr_src[p] = src[i];
    }
  }
}

// ---------------- D7: layer-1 conv (R1-verified: LDS staging + LDS-transpose epilogue) ----------

template <bool AF32>
__global__ __launch_bounds__(256) void conv_mfma(
    const void* __restrict__ Aptr, const ushort_t* __restrict__ Wp,
    const float* __restrict__ bias,
    ushort_t* __restrict__ ZP, int Kp) {
  __shared__ short smem[64 * SROW + 208 * SROW];
  __shared__ float bias_s[104];
  short* alds = smem;
  short* blds = smem + 64 * SROW;

  int tid = threadIdx.x;
  int n0 = blockIdx.x * 64;
  if (tid < 100) bias_s[tid] = bias[tid];

  f32x4 acc[13];
#pragma unroll
  for (int b = 0; b < 13; ++b) acc[b] = (f32x4)0.f;

  int w = tid >> 6, lane = tid & 63, q = lane >> 4, m16 = lane & 15;

  int ar[2], aq[2];
#pragma unroll
  for (int u = 0; u < 2; ++u) { int c = tid + u * 256; ar[u] = c >> 3; aq[u] = c & 7; }

  bf16x8 areg[2], breg[7];

  auto load_chunk = [&](int k0) {
#pragma unroll
    for (int u = 0; u < 2; ++u) {
      int node = n0 + ar[u];
      int k = k0 + aq[u] * 8;
      bf16x8 val = (bf16x8)0;
      if (AF32) {
        if (node < N_NODES && k < 336) {
          const float* p = (const float*)Aptr + (size_t)node * 336 + k;
          float4 f0 = *(const float4*)p;
          float4 f1 = *(const float4*)(p + 4);
          val[0] = (short)f2bf(f0.x); val[1] = (short)f2bf(f0.y);
          val[2] = (short)f2bf(f0.z); val[3] = (short)f2bf(f0.w);
          val[4] = (short)f2bf(f1.x); val[5] = (short)f2bf(f1.y);
          val[6] = (short)f2bf(f1.z); val[7] = (short)f2bf(f1.w);
        }
      } else {
        if (node < N_NODES)
          val = *(const bf16x8*)((const short*)Aptr + (size_t)node * 128 + k);
      }
      areg[u] = val;
    }
#pragma unroll
    for (int u = 0; u < 7; ++u) {
      int c = tid + u * 256;
      if (c < 1664) {
        int r = c >> 3, qq = c & 7;
        breg[u] = *(const bf16x8*)((const short*)Wp + (size_t)r * Kp + k0 + qq * 8);
      }
    }
  };

  load_chunk(0);

  for (int k0 = 0; k0 < Kp; k0 += 64) {
#pragma unroll
    for (int u = 0; u < 2; ++u)
      *(bf16x8*)&alds[ar[u] * SROW + aq[u] * 8] = areg[u];
#pragma unroll
    for (int u = 0; u < 7; ++u) {
      int c = tid + u * 256;
      if (c < 1664) {
        int r = c >> 3, qq = c & 7;
        *(bf16x8*)&blds[r * SROW + qq * 8] = breg[u];
      }
    }
    __syncthreads();
    if (k0 + 64 < Kp) load_chunk(k0 + 64);
#pragma unroll
    for (int s = 0; s < 2; ++s) {
      bf16x8 a = *(const bf16x8*)&alds[(w * 16 + m16) * SROW + s * 32 + q * 8];
#pragma unroll
      for (int b = 0; b < 13; ++b) {
        bf16x8 bf = *(const bf16x8*)&blds[(b * 16 + m16) * SROW + s * 32 + q * 8];
        acc[b] = __builtin_amdgcn_mfma_f32_16x16x32_bf16(a, bf, acc[b], 0, 0, 0);
      }
    }
    __syncthreads();
  }

  // epilogue: zero pad cols, transpose through LDS, full-line coalesced stores
  short* ep = smem;
#pragma unroll
  for (int j = 0; j < 9; ++j) {        // zero ep region (64*EPS shorts = 2112 uint4)
    int i = tid + j * 256;
    if (i < 64 * EPS / 8) *(uint4*)&ep[i * 8] = make_uint4(0u, 0u, 0u, 0u);
  }
  __syncthreads();
#pragma unroll
  for (int b = 0; b < 13; ++b) {
    int n = b * 16 + m16;
    if (n < 200) {
      int c = (n < 100) ? n : (n + 28);
      float add = (n < 100) ? 0.f : bias_s[(n - 100) & 127];
#pragma unroll
      for (int r = 0; r < 4; ++r) {
        int row = w * 16 + q * 4 + r;
        ep[row * EPS + c] = (short)f2bf(acc[b][r] + add);
      }
    }
  }
  __syncthreads();
#pragma unroll
  for (int j = 0; j < 8; ++j) {
    int i = tid + j * 256;
    int row = i >> 5, c16 = i & 31;
    int node = n0 + row;
    if (node < N_NODES) {
      *(uint4*)(ZP + (size_t)node * 256 + c16 * 8) =
          *(const uint4*)&ep[row * EPS + c16 * 8];
    }
  }
}

// ---------------- D8: gather1 — R10: 8 dsts/wave streaming (was 16: occupancy-starved) --------
// R9 lesson: scalar-addressed streaming cut VALU (25->14%) but 16 dsts/wave halved wave
// count -> occupancy 22%, BW 1.63 TB/s, net regression. 8 dsts/wave doubles waves (6250)
// at same per-edge cost. 50000 % 8 == 0 -> all in-range waves full.

__global__ __launch_bounds__(256) void gather_stream(
    const ushort_t* __restrict__ ZP,
    const int* __restrict__ offs, const int* __restrict__ csr,
    ushort_t* __restrict__ H) {
  int lane = threadIdx.x & 63;
  int wid = threadIdx.x >> 6;
  int d0 = __builtin_amdgcn_readfirstlane(blockIdx.x * 32 + wid * 8);
  if (d0 >= N_NODES) return;
  int offc = (lane < 50 ? lane : 49) * 2;   // clamped ushort offset (payload cols)

  float p0 = 0.f, p1 = 0.f;
  int d = d0;

  auto flushd = [&](int dd, float a0, float a1) {
    uint_t zr = *(const uint_t*)(ZP + (size_t)dd * 256 + 128 + offc);  // Zroot
    a0 += __uint_as_float(zr << 16);
    a1 += __uint_as_float(zr & 0xffff0000u);
    a0 = fmaxf(a0, 0.f); a1 = fmaxf(a1, 0.f);
    uint_t o = (uint_t)f2bf(a0) | ((uint_t)f2bf(a1) << 16);
    if (lane >= 50) o = 0u;
    *(uint_t*)(H + (size_t)dd * 128 + lane * 2) = o;
  };

  int s0 = offs[d0], e0 = offs[d0 + 8];
  int nextoff = offs[d + 1];
  uint_t bA[8], bB[8];
  auto issue = [&](uint_t (&buf)[8], int i) {
    int4 sa = *(const int4*)(csr + i);
    int4 sb = *(const int4*)(csr + i + 4);
    buf[0] = *(const uint_t*)(ZP + (size_t)sa.x * 256 + offc);
    buf[1] = *(const uint_t*)(ZP + (size_t)sa.y * 256 + offc);
    buf[2] = *(const uint_t*)(ZP + (size_t)sa.z * 256 + offc);
    buf[3] = *(const uint_t*)(ZP + (size_t)sa.w * 256 + offc);
    buf[4] = *(const uint_t*)(ZP + (size_t)sb.x * 256 + offc);
    buf[5] = *(const uint_t*)(ZP + (size_t)sb.y * 256 + offc);
    buf[6] = *(const uint_t*)(ZP + (size_t)sb.z * 256 + offc);
    buf[7] = *(const uint_t*)(ZP + (size_t)sb.w * 256 + offc);
  };
  auto cons = [&](uint_t (&buf)[8]) {
#pragma unroll
    for (int t = 0; t < 8; ++t) {
      p0 += __uint_as_float(buf[t] << 16);
      p1 += __uint_as_float(buf[t] & 0xffff0000u);
    }
  };

  int i = s0;
  if (i < e0) issue(bA, i);
  while (i < e0) {
    if (i + 8 < e0) issue(bB, i + 8);
    while (i == nextoff) { flushd(d, p0, p1); p0 = 0.f; p1 = 0.f; ++d; nextoff = offs[d + 1]; }
    cons(bA);
    i += 8;
    if (i >= e0) break;
    if (i + 8 < e0) issue(bA, i + 8);
    while (i == nextoff) { flushd(d, p0, p1); p0 = 0.f; p1 = 0.f; ++d; nextoff = offs[d + 1]; }
    cons(bB);
    i += 8;
  }
  while (d < d0 + 8) { flushd(d, p0, p1); p0 = 0.f; p1 = 0.f; ++d; }
}

// ---------------- D9-12: fused layer — R10: 32-dst block, 8 dsts/wave, wave-pair MFMA ----------
// Block = 256 thr / 4 waves / 32 dsts; grid 1563 (6.1 blocks/CU), LDS 17.9KB -> 8 blocks/CU
// residency cap (vs R9's 4). Wave w gathers its 8 dsts into A rows [w*8, w*8+8); MFMA:
// wave w computes nodes [(w>>1)*16,+16) x W-rows [(w&1)*64,+64) (4 frags, same verified
// swapped-operand convention); epilogue transpose + coalesced 256B row stores.

__global__ __launch_bounds__(256) void fused_stream(
    const ushort_t* __restrict__ Hin,
    const ushort_t* __restrict__ Wf,    // [128][256] bf16
    const float* __restrict__ bias,     // [100]
    const int* __restrict__ offs, const int* __restrict__ csr,
    ushort_t* __restrict__ Hout) {
  __shared__ short alds[32 * AST2];
  __shared__ __align__(16) float bias_s[128];

  int tid = threadIdx.x;
  int lane = tid & 63, wid = tid >> 6;
  int q = lane >> 4, m16 = lane & 15;
  if (tid < 128) bias_s[tid] = (tid < 100) ? bias[tid] : 0.f;

  int bd0 = blockIdx.x * 32;
  int d0 = __builtin_amdgcn_readfirstlane(bd0 + wid * 8);

  float p0 = 0.f, p1 = 0.f;
  auto flushA = [&](int dd, float a0, float a1) {
    uint_t o = (uint_t)f2bf(a0) | ((uint_t)f2bf(a1) << 16);
    *(uint_t*)&alds[(dd - bd0) * AST2 + lane * 2] = o;
  };

  if (d0 < N_NODES) {
    int s0 = offs[d0], e0 = offs[d0 + 8];   // 50000%8==0: in-range waves are full
    int d = d0;
    int nextoff = offs[d + 1];
    uint_t bA[8], bB[8];
    auto issue = [&](uint_t (&buf)[8], int i) {
      int4 sa = *(const int4*)(csr + i);
      int4 sb = *(const int4*)(csr + i + 4);
      buf[0] = *(const uint_t*)(Hin + (size_t)sa.x * 128 + lane * 2);
      buf[1] = *(const uint_t*)(Hin + (size_t)sa.y * 128 + lane * 2);
      buf[2] = *(const uint_t*)(Hin + (size_t)sa.z * 128 + lane * 2);
      buf[3] = *(const uint_t*)(Hin + (size_t)sa.w * 128 + lane * 2);
      buf[4] = *(const uint_t*)(Hin + (size_t)sb.x * 128 + lane * 2);
      buf[5] = *(const uint_t*)(Hin + (size_t)sb.y * 128 + lane * 2);
      buf[6] = *(const uint_t*)(Hin + (size_t)sb.z * 128 + lane * 2);
      buf[7] = *(const uint_t*)(Hin + (size_t)sb.w * 128 + lane * 2);
    };
    auto cons = [&](uint_t (&buf)[8]) {
#pragma unroll
      for (int t = 0; t < 8; ++t) {
        p0 += __uint_as_float(buf[t] << 16);
        p1 += __uint_as_float(buf[t] & 0xffff0000u);
      }
    };
    int i = s0;
    if (i < e0) issue(bA, i);
    while (i < e0) {
      if (i + 8 < e0) issue(bB, i + 8);
      while (i == nextoff) { flushA(d, p0, p1); p0 = 0.f; p1 = 0.f; ++d; nextoff = offs[d + 1]; }
      cons(bA);
      i += 8;
      if (i >= e0) break;
      if (i + 8 < e0) issue(bA, i + 8);
      while (i == nextoff) { flushA(d, p0, p1); p0 = 0.f; p1 = 0.f; ++d; nextoff = offs[d + 1]; }
      cons(bB);
      i += 8;
    }
    while (d < d0 + 8) { flushA(d, p0, p1); p0 = 0.f; p1 = 0.f; ++d; }
  } else {
    for (int dd = d0; dd < d0 + 8; ++dd) flushA(dd, 0.f, 0.f);
  }

  // own-h copy: A-tile cols 128..255 (H pad cols 100..127 are zero)
  for (int r = 0; r < 8; ++r) {
    int dd = d0 + r;
    int srcrow = (dd < N_NODES) ? dd : SENT;
    uint_t hv = *(const uint_t*)(Hin + (size_t)srcrow * 128 + lane * 2);
    *(uint_t*)&alds[(dd - bd0) * AST2 + 128 + lane * 2] = hv;
  }
  __syncthreads();

  // MFMA: wave (sub, half): nodes [sub*16,+16) x W-rows [half*64,+64), K=256
  int sub = wid >> 1, half = wid & 1;
  f32x4 acc[4];
#pragma unroll
  for (int wb = 0; wb < 4; ++wb) acc[wb] = (f32x4)0.f;
#pragma unroll
  for (int kb = 0; kb < 8; ++kb) {
    bf16x8 af = *(const bf16x8*)&alds[(sub * 16 + m16) * AST2 + kb * 32 + q * 8];
#pragma unroll
    for (int wb = 0; wb < 4; ++wb) {
      bf16x8 wf = *(const bf16x8*)(Wf + (size_t)(half * 64 + wb * 16 + m16) * 256 + kb * 32 + q * 8);
      acc[wb] = __builtin_amdgcn_mfma_f32_16x16x32_bf16(wf, af, acc[wb], 0, 0, 0);
    }
  }
  __syncthreads();   // all A-tile reads done; reuse alds as epilogue buffer

  // transpose epilogue: ep[node row][wrow col], bias+relu+bf16
#pragma unroll
  for (int wb = 0; wb < 4; ++wb) {
    int col0 = half * 64 + wb * 16 + q * 4;
    float4 bb = *(const float4*)&bias_s[col0];   // zeros for col0 >= 100
    ushort4 v;
    v.x = f2bf(fmaxf(acc[wb][0] + bb.x, 0.f));
    v.y = f2bf(fmaxf(acc[wb][1] + bb.y, 0.f));
    v.z = f2bf(fmaxf(acc[wb][2] + bb.z, 0.f));
    v.w = f2bf(fmaxf(acc[wb][3] + bb.w, 0.f));
    *(ushort4*)&alds[(sub * 16 + m16) * AST2 + col0] = v;
  }
  __syncthreads();

  // coalesced stores: 32 rows x 128 shorts = 512 uint4
#pragma unroll
  for (int j = 0; j < 2; ++j) {
    int i2 = tid + j * 256;
    int row = i2 >> 4, c = i2 & 15;
    int node = bd0 + row;
    if (node < N_NODES)
      *(uint4*)(Hout + (size_t)node * 128 + c * 8) = *(const uint4*)&alds[row * AST2 + c * 8];
  }
}

// ---------------- D13: fused pool + MLP head ----------------

__global__ __launch_bounds__(1024) void pool_mlp(
    const ushort_t* __restrict__ H, const int* __restrict__ batch,
    const float* __restrict__ lw1, const float* __restrict__ lb1,
    const float* __restrict__ lw2, const float* __restrict__ lb2,
    const float* __restrict__ lw3, const float* __restrict__ lb3,
    float* __restrict__ out) {
  int g = blockIdx.x;
  int t = threadIdx.x;
  int lo = 0, hi = N_NODES;
  while (lo < hi) { int mid = (lo + hi) >> 1; if (batch[mid] < g) lo = mid + 1; else hi = mid; }
  int s = lo;
  hi = N_NODES;
  while (lo < hi) { int mid = (lo + hi) >> 1; if (batch[mid] <= g) lo = mid + 1; else hi = mid; }
  int e = lo;

  int row = t >> 6;      // 16 node-rows
  int lane = t & 63;
  int off = (lane < 50 ? lane : 49) * 2;
  float a0 = 0.f, a1 = 0.f;
  for (int n = s + row; n < e; n += 16) {
    uint_t z = *(const uint_t*)(H + (size_t)n * 128 + off);
    a0 += __uint_as_float(z << 16);
    a1 += __uint_as_float(z & 0xffff0000u);
  }
  __shared__ float sh[16][104];
  __shared__ float r0[F], r1[F], r2[F];
  if (lane < 50) { sh[row][lane * 2] = a0; sh[row][lane * 2 + 1] = a1; }
  __syncthreads();
  if (t < F) {
    float acc = 0.f;
#pragma unroll
    for (int r = 0; r < 16; ++r) acc += sh[r][t];
    int cnt = e - s;
    float d = (cnt > 0) ? (float)cnt : 1.f;
    r0[t] = acc / d;
  }
  __syncthreads();
  if (t < F) {
    float sv = lb1[t];
    for (int k = 0; k < F; ++k) sv += r0[k] * lw1[t * F + k];
    r1[t] = fmaxf(sv, 0.f);
  }
  __syncthreads();
  if (t < F) {
    float sv = lb2[t];
    for (int k = 0; k < F; ++k) sv += r1[k] * lw2[t * F + k];
    r2[t] = fmaxf(sv, 0.f);
  }
  __syncthreads();
  if (t < 29) {
    float sv = lb3[t];
    for (int k = 0; k < F; ++k) sv += r2[k] * lw3[t * F + k];
    out[g * 29 + t] = sv;
  }
}

// ---------------- launch ------------------------------------------------------------------------

extern "C" void kernel_launch(void* const* d_in, const int* in_sizes, int n_in,
                              void* d_out, int out_size, void* d_ws, size_t ws_size,
                              hipStream_t stream) {
  const float* x       = (const float*)d_in[0];
  const int*   ei      = (const int*)d_in[1];
  const int*   batch   = (const int*)d_in[2];
  const float* w1_rel  = (const float*)d_in[3];
  const float* w1_root = (const float*)d_in[4];
  const float* b1      = (const float*)d_in[5];
  const float* w_rel   = (const float*)d_in[6];
  const float* w_root  = (const float*)d_in[7];
  const float* bvec    = (const float*)d_in[8];
  const float* lw1     = (const float*)d_in[9];
  const float* lb1     = (const float*)d_in[10];
  const float* lw2     = (const float*)d_in[11];
  const float* lb2     = (const float*)d_in[12];
  const float* lw3     = (const float*)d_in[13];
  const float* lb3     = (const float*)d_in[14];
  float* out = (float*)d_out;

  // workspace layout (sentinel row at index N_NODES in H1/H2/ZP)
  char* ws = (char*)d_ws;
  size_t o = 0;
  auto alloc = [&](size_t bytes) { void* p = ws + o; o = (o + bytes + 511) & ~(size_t)511; return p; };
  ushort_t* H1   = (ushort_t*)alloc((size_t)(N_NODES + 64) * 128 * 2);
  ushort_t* H2   = (ushort_t*)alloc((size_t)(N_NODES + 64) * 128 * 2);
  ushort_t* ZP   = (ushort_t*)alloc((size_t)(N_NODES + 1) * 256 * 2);
  ushort_t* Wp1  = (ushort_t*)alloc((size_t)208 * 384 * 2);
  ushort_t* Wf   = (ushort_t*)alloc((size_t)4 * 128 * 256 * 2);
  int* cnt    = (int*)alloc((size_t)SCAN_PAD * 4);
  int* excl   = (int*)alloc((size_t)SCAN_PAD * 4);
  int* bsum   = (int*)alloc((size_t)128 * 4);
  int* offs   = (int*)alloc((size_t)(N_NODES + 1) * 4);
  int* cursor = (int*)alloc((size_t)(N_NODES + 1) * 4);
  int* csr    = (int*)alloc((size_t)CSR_CAP * 4);

  const int E = N_EDGES;
  const int* srcv = ei;
  const int* dstv = ei + E;

  pack_all<<<1052, 256, 0, stream>>>(w1_rel, w1_root, w_rel, w_root, Wp1, Wf, cnt, csr, ZP, H1, H2);
  hist_kernel<<<HIST_BLOCKS, 256, 0, stream>>>(dstv, cnt, E);
  scan1_kernel<<<SCAN_NB, SCAN_B, 0, stream>>>(cnt, excl, bsum);
  scan2_kernel<<<1, 128, 0, stream>>>(bsum);
  scan3_kernel<<<SCAN_NB, SCAN_B, 0, stream>>>(excl, bsum, offs, cursor);
  fill_kernel<<<HIST_BLOCKS, 256, 0, stream>>>(srcv, dstv, cursor, csr, E);

  int mmgrid = (N_NODES + 63) / 64;  // 782
  conv_mfma<true><<<mmgrid, 256, 0, stream>>>(x, Wp1, b1, ZP, 384);
  gather_stream<<<(N_NODES + 31) / 32, 256, 0, stream>>>(ZP, offs, csr, H1);

  const ushort_t* hin = H1;
  ushort_t* hout = H2;
  for (int l = 0; l < 4; ++l) {
    fused_stream<<<(N_NODES + 31) / 32, 256, 0, stream>>>(hin, Wf + (size_t)l * 128 * 256,
                                                          bvec + (size_t)l * F, offs, csr, hout);
    const ushort_t* tmp = hout; hout = (ushort_t*)hin; hin = tmp;
  }
  // after 4 swaps hin == H1
  pool_mlp<<<N_GRAPHS, 1024, 0, stream>>>(hin, batch, lw1, lb1, lw2, lb2, lw3, lb3, out);
}